// Round 5
// baseline (620.229 us; speedup 1.0000x reference)
//
#include <hip/hip_runtime.h>
#include <hip/hip_bf16.h>

#define D_MODEL 256
#define N_ROWS  262144      // B * FEATS_PER_IMAGE
#define N_Q     1024        // B * Q_PER_IMAGE

typedef __attribute__((ext_vector_type(8))) short short8;
typedef __attribute__((ext_vector_type(16))) float floatx16;

static __device__ __forceinline__ short f2bf(float x) {
    union { __hip_bfloat16 h; short s; } u;
    u.h = __float2bfloat16(x);
    return u.s;
}

// ---------------------------------------------------------------------------
// Kernel 1: 4-layer MLP on queries, fp32 compute, bf16 output to workspace.
// (unchanged from verified baseline)
// ---------------------------------------------------------------------------
__global__ __launch_bounds__(256) void mlp_kernel(
    const float* __restrict__ q,
    const float* __restrict__ W1, const float* __restrict__ b1,
    const float* __restrict__ W2, const float* __restrict__ b2,
    const float* __restrict__ W3, const float* __restrict__ b3,
    const float* __restrict__ W4, const float* __restrict__ b4,
    __hip_bfloat16* __restrict__ xout)
{
    __shared__ float cur[4][D_MODEL];
    const int j = threadIdx.x;
    const int row0 = blockIdx.x * 4;

    #pragma unroll
    for (int i = 0; i < 4; i++)
        cur[i][j] = q[(long)(row0 + i) * D_MODEL + j];
    __syncthreads();

    const float* Ws[4] = { W1, W2, W3, W4 };
    const float* bs[4] = { b1, b2, b3, b4 };

    for (int l = 0; l < 4; l++) {
        const float4* wrow = (const float4*)(Ws[l] + (long)j * D_MODEL);
        float acc0 = bs[l][j];
        float acc1 = acc0, acc2 = acc0, acc3 = acc0;
        #pragma unroll 8
        for (int k = 0; k < D_MODEL / 4; k++) {
            float4 w  = wrow[k];
            float4 c0 = ((const float4*)cur[0])[k];
            float4 c1 = ((const float4*)cur[1])[k];
            float4 c2 = ((const float4*)cur[2])[k];
            float4 c3 = ((const float4*)cur[3])[k];
            acc0 += w.x*c0.x + w.y*c0.y + w.z*c0.z + w.w*c0.w;
            acc1 += w.x*c1.x + w.y*c1.y + w.z*c1.z + w.w*c1.w;
            acc2 += w.x*c2.x + w.y*c2.y + w.z*c2.z + w.w*c2.w;
            acc3 += w.x*c3.x + w.y*c3.y + w.z*c3.z + w.w*c3.w;
        }
        __syncthreads();
        if (l < 3) {
            cur[0][j] = fmaxf(acc0, 0.f);
            cur[1][j] = fmaxf(acc1, 0.f);
            cur[2][j] = fmaxf(acc2, 0.f);
            cur[3][j] = fmaxf(acc3, 0.f);
            __syncthreads();
        } else {
            xout[(long)(row0 + 0) * D_MODEL + j] = __float2bfloat16(acc0);
            xout[(long)(row0 + 1) * D_MODEL + j] = __float2bfloat16(acc1);
            xout[(long)(row0 + 2) * D_MODEL + j] = __float2bfloat16(acc2);
            xout[(long)(row0 + 3) * D_MODEL + j] = __float2bfloat16(acc3);
        }
    }
}

// ---------------------------------------------------------------------------
// Kernel 2: per-batch NT GEMM.  Back to the PROVEN serial per-block
// structure (stage -> barrier -> compute -> store), one 32-row tile per
// block — the concurrency comes from blocks/CU, not intra-block pipelining.
//
// Round-3 lesson: issue-early prefetch serializes (vmcnt is in-order: any
// B-load wait drains the older next-tile burst first) and 1024 blocks
// starved the grid.  Round-2 lesson: per-lane strided A-loads (64 lines/
// instr) collapse BW — staging must stay wave-contiguous (16 lines/instr).
//
// Concurrency math: per block ~26K cycles, HBM floor ~3.2K cyc/block/CU.
// 4 blocks/CU (old 33.8KB LDS + 116 regs) -> completion every 6.6K = 2x
// floor = the measured 2.3 TB/s.  This version: BM=32 (16.9 KB LDS), no
// regs held across compute, __launch_bounds__(256,6) -> 6 blocks/CU
// (total regs <= 85: ~48 VGPR + 32 AGPR acc).  Grid 8192 blocks.
// ---------------------------------------------------------------------------
#define APAD 264
#define BM   32

__global__ __launch_bounds__(256, 6) void logits_kernel(
    const float* __restrict__ F,            // [262144, 256] fp32
    const __hip_bfloat16* __restrict__ X,   // [1024, 256] bf16
    float* __restrict__ out)                // [262144, 256] fp32
{
    __shared__ __hip_bfloat16 As[BM * APAD];   // 16896 B

    const int t    = threadIdx.x;
    const int wave = t >> 6;
    const int lane = t & 63;
    const int m    = lane & 31;     // row-in-32 (A) / col-in-32 (B)
    const int kg   = lane >> 5;     // k-group: k offset = kg*8

    // XCD swizzle (bijective: 8192 % 8 == 0): each XCD gets a contiguous
    // 1024-block chunk = 32768 rows = half a batch -> one X-slice per XCD L2.
    int b = blockIdx.x;
    b = (b & 7) * (8192 / 8) + (b >> 3);

    const long row0  = (long)b * BM;
    const int  batch = (int)(row0 >> 16);       // 65536 rows per batch

    // ---- stage A tile: coalesced global fp32 -> bf16 LDS ----
    // 32x256 fp32 = 2048 float4; 8 per thread, wave-contiguous (1KB/instr).
    {
        const float4* Fb = (const float4*)(F + row0 * D_MODEL);
        #pragma unroll
        for (int i = 0; i < 8; i++) {
            const int flat = i * 256 + t;        // float4 index in 32x256 tile
            const int row  = flat >> 6;          // 64 float4 per row
            const int c4   = (flat & 63) << 2;   // float col
            float4 v = Fb[flat];
            union { ushort4 u; short s[4]; } w;
            w.s[0] = f2bf(v.x); w.s[1] = f2bf(v.y);
            w.s[2] = f2bf(v.z); w.s[3] = f2bf(v.w);
            *(ushort4*)(&As[row * APAD + c4]) = w.u;   // 8B write, 2-way = free
        }
    }
    __syncthreads();

    // ---- compute: wave tile 32 rows x 64 cols = 1x2 mfma_32x32x16 ----
    const __hip_bfloat16* a0 = &As[m * APAD + kg * 8];
    const __hip_bfloat16* bb =
        X + ((long)(batch << 8) + (wave << 6) + m) * D_MODEL + kg * 8;

    floatx16 acc0 = {0.f}, acc1 = {0.f};

    #pragma unroll 4
    for (int ks = 0; ks < 16; ks++) {
        const int k0 = ks * 16;
        short8 af  = *(const short8*)(a0 + k0);               // ds_read_b128
        short8 bf0 = *(const short8*)(bb + k0);               // L1/L2-hot
        short8 bf1 = *(const short8*)(bb + 32 * D_MODEL + k0);
        acc0 = __builtin_amdgcn_mfma_f32_32x32x16_bf16(af, bf0, acc0, 0, 0, 0);
        acc1 = __builtin_amdgcn_mfma_f32_32x32x16_bf16(af, bf1, acc1, 0, 0, 0);
    }

    // ---- store ----
    // C/D layout (m74/m101): col = lane&31, row = (reg&3)+8*(reg>>2)+4*(lane>>5)
    // Nontemporal: out is never re-read; keep it from evicting F in L3.
    const long rbase   = row0 + 4 * kg;
    const int  colbase = (wave << 6) + m;
    #pragma unroll
    for (int reg = 0; reg < 16; reg++) {
        const int r = (reg & 3) + 8 * (reg >> 2);
        float* orow = out + (rbase + r) * D_MODEL + colbase;
        __builtin_nontemporal_store(acc0[reg], orow);
        __builtin_nontemporal_store(acc1[reg], orow + 32);
    }
}

extern "C" void kernel_launch(void* const* d_in, const int* in_sizes, int n_in,
                              void* d_out, int out_size, void* d_ws, size_t ws_size,
                              hipStream_t stream) {
    const float* queries = (const float*)d_in[0];
    const float* feats   = (const float*)d_in[1];
    // d_in[2] feature_indices, d_in[3] query_batch_offsets: not needed for values
    const float* W1 = (const float*)d_in[4];
    const float* b1 = (const float*)d_in[5];
    const float* W2 = (const float*)d_in[6];
    const float* b2 = (const float*)d_in[7];
    const float* W3 = (const float*)d_in[8];
    const float* b3 = (const float*)d_in[9];
    const float* W4 = (const float*)d_in[10];
    const float* b4 = (const float*)d_in[11];

    __hip_bfloat16* x_bf16 = (__hip_bfloat16*)d_ws;   // [1024, 256] bf16 = 512 KB

    mlp_kernel<<<N_Q / 4, 256, 0, stream>>>(queries, W1, b1, W2, b2, W3, b3, W4, b4, x_bf16);
    logits_kernel<<<N_ROWS / BM, 256, 0, stream>>>(feats, x_bf16, (float*)d_out);
}

// Round 6
// 618.352 us; speedup vs baseline: 1.0030x; 1.0030x over previous
//
#include <hip/hip_runtime.h>
#include <hip/hip_bf16.h>

#define D_MODEL 256
#define N_ROWS  262144      // B * FEATS_PER_IMAGE
#define N_Q     1024        // B * Q_PER_IMAGE

typedef __attribute__((ext_vector_type(8))) short short8;
typedef __attribute__((ext_vector_type(16))) float floatx16;

static __device__ __forceinline__ short f2bf(float x) {
    union { __hip_bfloat16 h; short s; } u;
    u.h = __float2bfloat16(x);
    return u.s;
}

// ---------------------------------------------------------------------------
// Kernel 1: 4-layer MLP on queries, fp32 compute, bf16 output to workspace.
// (unchanged from verified baseline)
// ---------------------------------------------------------------------------
__global__ __launch_bounds__(256) void mlp_kernel(
    const float* __restrict__ q,
    const float* __restrict__ W1, const float* __restrict__ b1,
    const float* __restrict__ W2, const float* __restrict__ b2,
    const float* __restrict__ W3, const float* __restrict__ b3,
    const float* __restrict__ W4, const float* __restrict__ b4,
    __hip_bfloat16* __restrict__ xout)
{
    __shared__ float cur[4][D_MODEL];
    const int j = threadIdx.x;
    const int row0 = blockIdx.x * 4;

    #pragma unroll
    for (int i = 0; i < 4; i++)
        cur[i][j] = q[(long)(row0 + i) * D_MODEL + j];
    __syncthreads();

    const float* Ws[4] = { W1, W2, W3, W4 };
    const float* bs[4] = { b1, b2, b3, b4 };

    for (int l = 0; l < 4; l++) {
        const float4* wrow = (const float4*)(Ws[l] + (long)j * D_MODEL);
        float acc0 = bs[l][j];
        float acc1 = acc0, acc2 = acc0, acc3 = acc0;
        #pragma unroll 8
        for (int k = 0; k < D_MODEL / 4; k++) {
            float4 w  = wrow[k];
            float4 c0 = ((const float4*)cur[0])[k];
            float4 c1 = ((const float4*)cur[1])[k];
            float4 c2 = ((const float4*)cur[2])[k];
            float4 c3 = ((const float4*)cur[3])[k];
            acc0 += w.x*c0.x + w.y*c0.y + w.z*c0.z + w.w*c0.w;
            acc1 += w.x*c1.x + w.y*c1.y + w.z*c1.z + w.w*c1.w;
            acc2 += w.x*c2.x + w.y*c2.y + w.z*c2.z + w.w*c2.w;
            acc3 += w.x*c3.x + w.y*c3.y + w.z*c3.z + w.w*c3.w;
        }
        __syncthreads();
        if (l < 3) {
            cur[0][j] = fmaxf(acc0, 0.f);
            cur[1][j] = fmaxf(acc1, 0.f);
            cur[2][j] = fmaxf(acc2, 0.f);
            cur[3][j] = fmaxf(acc3, 0.f);
            __syncthreads();
        } else {
            xout[(long)(row0 + 0) * D_MODEL + j] = __float2bfloat16(acc0);
            xout[(long)(row0 + 1) * D_MODEL + j] = __float2bfloat16(acc1);
            xout[(long)(row0 + 2) * D_MODEL + j] = __float2bfloat16(acc2);
            xout[(long)(row0 + 3) * D_MODEL + j] = __float2bfloat16(acc3);
        }
    }
}

// ---------------------------------------------------------------------------
// Kernel 2: per-batch NT GEMM, serial per-block structure
// (stage -> barrier -> compute -> store), one 32-row tile per block.
//
// ROUND-6 A/B: identical to round 5 EXCEPT plain write-back stores instead
// of __builtin_nontemporal_store.  Evidence: every nt-store variant
// (rounds 2/3/5 — different structures, occupancy 38% vs 83%) capped at
// 1500-1650 GB/s; the only plain-store variant (round 0) hit 2302 GB/s.
// Theory: nt bypasses L2 write-back buffering, so the 262 MB store stream
// (the largest traffic component) drains synchronously at HBM granularity
// and stalls wave issue; plain stores complete into L2 and drain async.
//
// Held constant from round 5: BM=32, APAD=264 (0 conflicts), wave-
// contiguous staging (round-2 lesson: per-lane strided gathers collapse
// BW), no intra-block prefetch (round-3 lesson: in-order vmcnt serializes
// it), launch_bounds(256,6) reg diet (VGPR 32, occupancy 83%), bijective
// XCD swizzle (8192 % 8 == 0).
// ---------------------------------------------------------------------------
#define APAD 264
#define BM   32

__global__ __launch_bounds__(256, 6) void logits_kernel(
    const float* __restrict__ F,            // [262144, 256] fp32
    const __hip_bfloat16* __restrict__ X,   // [1024, 256] bf16
    float* __restrict__ out)                // [262144, 256] fp32
{
    __shared__ __hip_bfloat16 As[BM * APAD];   // 16896 B

    const int t    = threadIdx.x;
    const int wave = t >> 6;
    const int lane = t & 63;
    const int m    = lane & 31;     // row-in-32 (A) / col-in-32 (B)
    const int kg   = lane >> 5;     // k-group: k offset = kg*8

    // XCD swizzle (bijective: 8192 % 8 == 0): each XCD gets a contiguous
    // 1024-block chunk = 32768 rows = half a batch -> one X-slice per XCD L2.
    int b = blockIdx.x;
    b = (b & 7) * (8192 / 8) + (b >> 3);

    const long row0  = (long)b * BM;
    const int  batch = (int)(row0 >> 16);       // 65536 rows per batch

    // ---- stage A tile: coalesced global fp32 -> bf16 LDS ----
    // 32x256 fp32 = 2048 float4; 8 per thread, wave-contiguous (1KB/instr).
    {
        const float4* Fb = (const float4*)(F + row0 * D_MODEL);
        #pragma unroll
        for (int i = 0; i < 8; i++) {
            const int flat = i * 256 + t;        // float4 index in 32x256 tile
            const int row  = flat >> 6;          // 64 float4 per row
            const int c4   = (flat & 63) << 2;   // float col
            float4 v = Fb[flat];
            union { ushort4 u; short s[4]; } w;
            w.s[0] = f2bf(v.x); w.s[1] = f2bf(v.y);
            w.s[2] = f2bf(v.z); w.s[3] = f2bf(v.w);
            *(ushort4*)(&As[row * APAD + c4]) = w.u;   // 8B write, 2-way = free
        }
    }
    __syncthreads();

    // ---- compute: wave tile 32 rows x 64 cols = 1x2 mfma_32x32x16 ----
    const __hip_bfloat16* a0 = &As[m * APAD + kg * 8];
    const __hip_bfloat16* bb =
        X + ((long)(batch << 8) + (wave << 6) + m) * D_MODEL + kg * 8;

    floatx16 acc0 = {0.f}, acc1 = {0.f};

    #pragma unroll 4
    for (int ks = 0; ks < 16; ks++) {
        const int k0 = ks * 16;
        short8 af  = *(const short8*)(a0 + k0);               // ds_read_b128
        short8 bf0 = *(const short8*)(bb + k0);               // L1/L2-hot
        short8 bf1 = *(const short8*)(bb + 32 * D_MODEL + k0);
        acc0 = __builtin_amdgcn_mfma_f32_32x32x16_bf16(af, bf0, acc0, 0, 0, 0);
        acc1 = __builtin_amdgcn_mfma_f32_32x32x16_bf16(af, bf1, acc1, 0, 0, 0);
    }

    // ---- store (plain write-back — the round-6 experimental variable) ----
    // C/D layout (m74/m101): col = lane&31, row = (reg&3)+8*(reg>>2)+4*(lane>>5)
    const long rbase   = row0 + 4 * kg;
    const int  colbase = (wave << 6) + m;
    #pragma unroll
    for (int reg = 0; reg < 16; reg++) {
        const int r = (reg & 3) + 8 * (reg >> 2);
        float* orow = out + (rbase + r) * D_MODEL + colbase;
        orow[0]  = acc0[reg];
        orow[32] = acc1[reg];
    }
}

extern "C" void kernel_launch(void* const* d_in, const int* in_sizes, int n_in,
                              void* d_out, int out_size, void* d_ws, size_t ws_size,
                              hipStream_t stream) {
    const float* queries = (const float*)d_in[0];
    const float* feats   = (const float*)d_in[1];
    // d_in[2] feature_indices, d_in[3] query_batch_offsets: not needed for values
    const float* W1 = (const float*)d_in[4];
    const float* b1 = (const float*)d_in[5];
    const float* W2 = (const float*)d_in[6];
    const float* b2 = (const float*)d_in[7];
    const float* W3 = (const float*)d_in[8];
    const float* b3 = (const float*)d_in[9];
    const float* W4 = (const float*)d_in[10];
    const float* b4 = (const float*)d_in[11];

    __hip_bfloat16* x_bf16 = (__hip_bfloat16*)d_ws;   // [1024, 256] bf16 = 512 KB

    mlp_kernel<<<N_Q / 4, 256, 0, stream>>>(queries, W1, b1, W2, b2, W3, b3, W4, b4, x_bf16);
    logits_kernel<<<N_ROWS / BM, 256, 0, stream>>>(feats, x_bf16, (float*)d_out);
}

// Round 7
// 529.239 us; speedup vs baseline: 1.1719x; 1.1684x over previous
//
#include <hip/hip_runtime.h>
#include <hip/hip_bf16.h>

#define D_MODEL 256
#define N_ROWS  262144      // B * FEATS_PER_IMAGE
#define N_Q     1024        // B * Q_PER_IMAGE

typedef __attribute__((ext_vector_type(8))) short short8;
typedef __attribute__((ext_vector_type(16))) float floatx16;

static __device__ __forceinline__ short f2bf(float x) {
    union { __hip_bfloat16 h; short s; } u;
    u.h = __float2bfloat16(x);
    return u.s;
}

// ---------------------------------------------------------------------------
// Kernel 1: 4-layer MLP on queries, fp32 compute, bf16 output to workspace.
// ROUND-7 change: output written in PACKED MFMA-B-fragment order so the
// logits kernel's B-loads are lane-contiguous (no strided gathers).
// Element X[r][j] -> idx = (r>>5)*8192 + (j>>4)*512 + ((j>>3)&1)*256
//                        + (r&31)*8 + (j&7)
// (chunk = (r>>5)*16 + (j>>4) selects {batch,wave,frag,ks}; within a chunk,
//  lane kg*32+m at offset lane*8 holds k = ks*16+kg*8 .. +8 of row
//  w*64+f*32+m — exactly the mfma_32x32x16 B-fragment layout.)
// ---------------------------------------------------------------------------
__global__ __launch_bounds__(256) void mlp_kernel(
    const float* __restrict__ q,
    const float* __restrict__ W1, const float* __restrict__ b1,
    const float* __restrict__ W2, const float* __restrict__ b2,
    const float* __restrict__ W3, const float* __restrict__ b3,
    const float* __restrict__ W4, const float* __restrict__ b4,
    __hip_bfloat16* __restrict__ xout)
{
    __shared__ float cur[4][D_MODEL];
    const int j = threadIdx.x;
    const int row0 = blockIdx.x * 4;

    #pragma unroll
    for (int i = 0; i < 4; i++)
        cur[i][j] = q[(long)(row0 + i) * D_MODEL + j];
    __syncthreads();

    const float* Ws[4] = { W1, W2, W3, W4 };
    const float* bs[4] = { b1, b2, b3, b4 };

    // packed-index pieces that depend only on j (the k-dim of X):
    const int jpart = ((j >> 4) << 9) + (((j >> 3) & 1) << 8) + (j & 7);

    for (int l = 0; l < 4; l++) {
        const float4* wrow = (const float4*)(Ws[l] + (long)j * D_MODEL);
        float acc0 = bs[l][j];
        float acc1 = acc0, acc2 = acc0, acc3 = acc0;
        #pragma unroll 8
        for (int k = 0; k < D_MODEL / 4; k++) {
            float4 w  = wrow[k];
            float4 c0 = ((const float4*)cur[0])[k];
            float4 c1 = ((const float4*)cur[1])[k];
            float4 c2 = ((const float4*)cur[2])[k];
            float4 c3 = ((const float4*)cur[3])[k];
            acc0 += w.x*c0.x + w.y*c0.y + w.z*c0.z + w.w*c0.w;
            acc1 += w.x*c1.x + w.y*c1.y + w.z*c1.z + w.w*c1.w;
            acc2 += w.x*c2.x + w.y*c2.y + w.z*c2.z + w.w*c2.w;
            acc3 += w.x*c3.x + w.y*c3.y + w.z*c3.z + w.w*c3.w;
        }
        __syncthreads();
        if (l < 3) {
            cur[0][j] = fmaxf(acc0, 0.f);
            cur[1][j] = fmaxf(acc1, 0.f);
            cur[2][j] = fmaxf(acc2, 0.f);
            cur[3][j] = fmaxf(acc3, 0.f);
            __syncthreads();
        } else {
            const float accs[4] = { acc0, acc1, acc2, acc3 };
            #pragma unroll
            for (int i = 0; i < 4; i++) {
                const int r = row0 + i;
                const long idx = ((long)(r >> 5) << 13) + jpart + ((r & 31) << 3);
                xout[idx] = __float2bfloat16(accs[i]);
            }
        }
    }
}

// ---------------------------------------------------------------------------
// Kernel 2: per-batch NT GEMM — EXACT round-0 structure (the 175 us best:
// BM=64, 2x2 mfma_32x32x16 per wave, 4096 blocks, plain stores, no swizzle),
// with ONE change: B-loads read the packed-fragment X, so they are
// lane-contiguous (base + lane*16, 16 sequential lines/instr) instead of
// 32-line strided gathers (64 lanes at 512 B row stride).  Evidence: R6
// showed occupancy 83% doesn't help and stores cost only 5% — the hidden
// limiter signature (all pipes idle) points at vector-memory request rate,
// and gather count is the variable that tracks the BM=64 vs BM=32 delta.
// ---------------------------------------------------------------------------
#define APAD 264

__global__ __launch_bounds__(256) void logits_kernel(
    const float* __restrict__ F,            // [262144, 256] fp32
    const __hip_bfloat16* __restrict__ Xp,  // [1024*256] bf16, packed fragments
    float* __restrict__ out)                // [262144, 256] fp32
{
    __shared__ __hip_bfloat16 As[64 * APAD];   // 33792 B

    const int t    = threadIdx.x;
    const int wave = t >> 6;
    const int lane = t & 63;
    const int m    = lane & 31;     // row-in-32 (A) / col-in-32 (B)
    const int kg   = lane >> 5;     // k-group: k offset = kg*8

    const long row0  = (long)blockIdx.x * 64;
    const int  batch = (int)(row0 >> 16);       // 65536 rows per batch

    // ---- stage A tile: coalesced global fp32 -> bf16 LDS ----
    const float* Fbase = F + row0 * D_MODEL;
    #pragma unroll
    for (int i = 0; i < 16; i++) {
        const int flat = i * 256 + t;        // float4 index within 64x256 tile
        const int row  = flat >> 6;          // 64 float4 per row
        const int c4   = (flat & 63) << 2;   // float col
        float4 v = *(const float4*)(Fbase + (size_t)flat * 4);
        union { ushort4 u; short s[4]; } w;
        w.s[0] = f2bf(v.x); w.s[1] = f2bf(v.y);
        w.s[2] = f2bf(v.z); w.s[3] = f2bf(v.w);
        *(ushort4*)(&As[row * APAD + c4]) = w.u;   // 8B write, 2-way bank = free
    }
    __syncthreads();

    // ---- compute: wave tile 64x64 = 2x2 mfma_32x32x16 ----
    const __hip_bfloat16* a0 = &As[m * APAD + kg * 8];
    const __hip_bfloat16* a1 = a0 + 32 * APAD;
    // packed B: chunk = batch*128 + wave*32 + f*16 + ks, 512 elems/chunk,
    // lane's fragment at elem lane*8 within the chunk.
    const __hip_bfloat16* b0 =
        Xp + ((size_t)batch * 128 + (size_t)wave * 32) * 512 + lane * 8;
    const __hip_bfloat16* b1 = b0 + 16 * 512;   // f=1 fragments

    floatx16 acc00 = {0.f}, acc01 = {0.f}, acc10 = {0.f}, acc11 = {0.f};

    #pragma unroll 4
    for (int ks = 0; ks < 16; ks++) {
        const int k0 = ks * 16;   // A: 16 k per step; this lane covers k0+kg*8..+8

        short8 af0 = *(const short8*)(a0 + k0);        // ds_read_b128
        short8 af1 = *(const short8*)(a1 + k0);
        short8 bf0 = *(const short8*)(b0 + ks * 512);  // lane-contiguous, L2-hot
        short8 bf1 = *(const short8*)(b1 + ks * 512);

        acc00 = __builtin_amdgcn_mfma_f32_32x32x16_bf16(af0, bf0, acc00, 0, 0, 0);
        acc01 = __builtin_amdgcn_mfma_f32_32x32x16_bf16(af0, bf1, acc01, 0, 0, 0);
        acc10 = __builtin_amdgcn_mfma_f32_32x32x16_bf16(af1, bf0, acc10, 0, 0, 0);
        acc11 = __builtin_amdgcn_mfma_f32_32x32x16_bf16(af1, bf1, acc11, 0, 0, 0);
    }

    // C/D layout (verified m74/m101): col = lane&31, row = (reg&3)+8*(reg>>2)+4*(lane>>5)
    const int colbase = (wave << 6) + m;
    #pragma unroll
    for (int rt = 0; rt < 2; rt++) {
        const floatx16 accr0 = (rt == 0) ? acc00 : acc10;
        const floatx16 accr1 = (rt == 0) ? acc01 : acc11;
        const long rbase = row0 + rt * 32 + 4 * kg;
        #pragma unroll
        for (int reg = 0; reg < 16; reg++) {
            const int r = (reg & 3) + 8 * (reg >> 2);
            out[(rbase + r) * D_MODEL + colbase]      = accr0[reg];
            out[(rbase + r) * D_MODEL + colbase + 32] = accr1[reg];
        }
    }
}

extern "C" void kernel_launch(void* const* d_in, const int* in_sizes, int n_in,
                              void* d_out, int out_size, void* d_ws, size_t ws_size,
                              hipStream_t stream) {
    const float* queries = (const float*)d_in[0];
    const float* feats   = (const float*)d_in[1];
    // d_in[2] feature_indices, d_in[3] query_batch_offsets: not needed for values
    const float* W1 = (const float*)d_in[4];
    const float* b1 = (const float*)d_in[5];
    const float* W2 = (const float*)d_in[6];
    const float* b2 = (const float*)d_in[7];
    const float* W3 = (const float*)d_in[8];
    const float* b3 = (const float*)d_in[9];
    const float* W4 = (const float*)d_in[10];
    const float* b4 = (const float*)d_in[11];

    __hip_bfloat16* x_bf16 = (__hip_bfloat16*)d_ws;   // [1024*256] bf16 packed = 512 KB

    mlp_kernel<<<N_Q / 4, 256, 0, stream>>>(queries, W1, b1, W2, b2, W3, b3, W4, b4, x_bf16);
    logits_kernel<<<N_ROWS / 64, 256, 0, stream>>>(feats, x_bf16, (float*)d_out);
}